// Round 11
// baseline (251.102 us; speedup 1.0000x reference)
//
#include <hip/hip_runtime.h>
#include <stdint.h>

// Ground truth (established round 10): inputs are EXACTLY as the reference file
// says — x: f32 [32,2048,64], r_sigma: f32 [1], out: f32. The session's earlier
// bf16 inference came from misreading a 2%-relative threshold (1.91 = 0.02*95.5).
// Internally: cast to bf16 for MFMA (error << threshold), f32 accumulate/output.
#define T_DIM 2048
#define C_DIM 64
#define BT 128
#define BS 128
#define PS 136   // LDS row stride (ushorts): 272 B/row, 16B-aligned, free 2-way banking

typedef __bf16 bf16x8v __attribute__((ext_vector_type(8)));
typedef float f32x4 __attribute__((ext_vector_type(4)));

#if defined(__has_builtin)
#if __has_builtin(__builtin_amdgcn_exp2f)
#define EXP2F(x) __builtin_amdgcn_exp2f(x)
#else
#define EXP2F(x) exp2f(x)
#endif
#else
#define EXP2F(x) exp2f(x)
#endif

__device__ __forceinline__ unsigned short f32_to_bf16_rne(float f) {
  union { float f; unsigned int x; } v; v.f = f;
  unsigned int u = v.x;
  u += 0x7fffu + ((u >> 16) & 1u);
  return (unsigned short)(u >> 16);
}

// HW-verified 16x16x32 bf16 MFMA layouts (learn_hip m89/m91/m97/m120):
//   A-frag: A[m=lane&15][k=(lane>>4)*8+j];  B-frag: lane reads row n of B^T, k-contig
//   C/D: col=lane&15, row=(lane>>4)*4+reg

__global__ __launch_bounds__(256, 2)
void gauss_attn_f32(const float* __restrict__ x,
                    const float* __restrict__ rs,
                    float* __restrict__ out) {
  __shared__ __align__(16) unsigned short sm_xst[C_DIM * PS]; // Xs^T bf16: [c][s]
  __shared__ __align__(16) unsigned short sm_p[BT * PS];      // P bf16:    [t][s]
  __shared__ float sm_sT[BT];
  __shared__ float sm_sS[BS];
  __shared__ float sm_part[2 * BS];

  const int b    = blockIdx.y;
  const int t0   = blockIdx.x * BT;
  const int tid  = threadIdx.x;
  const int w    = tid >> 6;
  const int lane = tid & 63;
  const int l15  = lane & 15;
  const int quad = lane >> 4;

  float sigma = rs[0];
  if (!(sigma == sigma) || !(sigma >= 0.f) || sigma > 1e3f) sigma = 0.01f;
  const float c1 = sigma * 1.4426950408889634f; // sigma*log2(e)
  const float c2 = 2.0f * c1;

  const float* xb = x + (size_t)b * T_DIM * C_DIM;

  // ---- prologue: ||x_t||^2 (exact f32) for the block's 128 t-rows ----
  if (tid < BT) {
    const f32x4* r4 = (const f32x4*)(xb + (size_t)(t0 + tid) * C_DIM);
    float s = 0.f;
#pragma unroll
    for (int i = 0; i < 16; ++i) {
      f32x4 v = r4[i];
      s += v[0]*v[0] + v[1]*v[1] + v[2]*v[2] + v[3]*v[3];
    }
    sm_sT[tid] = s;
  }

  // ---- Q A-frags: t = t0 + w*32 + mt*16 + l15, c = kk*32 + quad*8 + j (bf16 cast) ----
  bf16x8v qf[2][2];
#pragma unroll
  for (int mt = 0; mt < 2; ++mt) {
    const float* qp = xb + (size_t)(t0 + w * 32 + mt * 16 + l15) * C_DIM + quad * 8;
#pragma unroll
    for (int kk = 0; kk < 2; ++kk) {
      f32x4 a0 = *(const f32x4*)(qp + kk * 32);
      f32x4 a1 = *(const f32x4*)(qp + kk * 32 + 4);
      union { unsigned short u[8]; bf16x8v v; } pk;
#pragma unroll
      for (int j = 0; j < 4; ++j) { pk.u[j] = f32_to_bf16_rne(a0[j]); pk.u[4+j] = f32_to_bf16_rne(a1[j]); }
      qf[mt][kk] = pk.v;
    }
  }

  __syncthreads();

  float sTr[2][4];
#pragma unroll
  for (int mt = 0; mt < 2; ++mt)
#pragma unroll
    for (int reg = 0; reg < 4; ++reg)
      sTr[mt][reg] = c1 * sm_sT[w * 32 + mt * 16 + quad * 4 + reg];

  f32x4 oacc[2][4];
#pragma unroll
  for (int mt = 0; mt < 2; ++mt)
#pragma unroll
    for (int nt = 0; nt < 4; ++nt)
#pragma unroll
      for (int r = 0; r < 4; ++r) oacc[mt][nt][r] = 0.f;

  const int sidx = tid & 127;
  const int h    = tid >> 7;

  for (int it = 0; it < T_DIM / BS; ++it) {
    const int s0 = it * BS;
    __syncthreads(); // prev iter's LDS reads done

    // ---- stage Xs^T (bf16) into LDS + |x_s|^2 partials (f32 exact) ----
    {
      float part = 0.f;
      const float* sp = xb + (size_t)(s0 + sidx) * C_DIM + h * 32;
#pragma unroll
      for (int r = 0; r < 8; ++r) {
        f32x4 v = *(const f32x4*)(sp + r * 4);
        part += v[0]*v[0] + v[1]*v[1] + v[2]*v[2] + v[3]*v[3];
        const int c0 = h * 32 + r * 4;
        sm_xst[(c0 + 0) * PS + sidx] = f32_to_bf16_rne(v[0]);
        sm_xst[(c0 + 1) * PS + sidx] = f32_to_bf16_rne(v[1]);
        sm_xst[(c0 + 2) * PS + sidx] = f32_to_bf16_rne(v[2]);
        sm_xst[(c0 + 3) * PS + sidx] = f32_to_bf16_rne(v[3]);
      }
      sm_part[h * BS + sidx] = part;
    }
    __syncthreads();
    if (tid < BS) sm_sS[tid] = sm_part[tid] + sm_part[BS + tid];
    __syncthreads();

    // ---- GEMM1: inner = Q * Xs^T; B-frags from global f32 (row s, c-contig) ----
    f32x4 pacc[2][8];
#pragma unroll
    for (int mt = 0; mt < 2; ++mt)
#pragma unroll
      for (int nt = 0; nt < 8; ++nt)
#pragma unroll
        for (int r = 0; r < 4; ++r) pacc[mt][nt][r] = 0.f;

#pragma unroll
    for (int nt = 0; nt < 8; ++nt) {
      const float* bp = xb + (size_t)(s0 + nt * 16 + l15) * C_DIM + quad * 8;
#pragma unroll
      for (int kk = 0; kk < 2; ++kk) {
        f32x4 b0 = *(const f32x4*)(bp + kk * 32);
        f32x4 b1 = *(const f32x4*)(bp + kk * 32 + 4);
        union { unsigned short u[8]; bf16x8v v; } pk;
#pragma unroll
        for (int j = 0; j < 4; ++j) { pk.u[j] = f32_to_bf16_rne(b0[j]); pk.u[4+j] = f32_to_bf16_rne(b1[j]); }
        pacc[0][nt] = __builtin_amdgcn_mfma_f32_16x16x32_bf16(qf[0][kk], pk.v, pacc[0][nt], 0, 0, 0);
        pacc[1][nt] = __builtin_amdgcn_mfma_f32_16x16x32_bf16(qf[1][kk], pk.v, pacc[1][nt], 0, 0, 0);
      }
    }

    // ---- K = exp2(min(c2*inner - c1(|t|^2+|s|^2), 0)) -> bf16 P[t][s] ----
#pragma unroll
    for (int nt = 0; nt < 8; ++nt) {
      const float sS = c1 * sm_sS[nt * 16 + l15];
#pragma unroll
      for (int mt = 0; mt < 2; ++mt) {
#pragma unroll
        for (int reg = 0; reg < 4; ++reg) {
          float arg = c2 * pacc[mt][nt][reg] - (sTr[mt][reg] + sS);
          arg = (arg < 0.f) ? arg : 0.f;
          float kv = EXP2F(arg);
          sm_p[(w * 32 + mt * 16 + quad * 4 + reg) * PS + nt * 16 + l15] = f32_to_bf16_rne(kv);
        }
      }
    }
    __syncthreads();

    // ---- GEMM2: O += P * Xs (A: sm_p rows; B: sm_xst rows; both s-contig b128) ----
#pragma unroll
    for (int kk = 0; kk < 4; ++kk) {
      bf16x8v af[2];
#pragma unroll
      for (int mt = 0; mt < 2; ++mt)
        af[mt] = *(const bf16x8v*)(sm_p + (w * 32 + mt * 16 + l15) * PS + kk * 32 + quad * 8);
#pragma unroll
      for (int nt = 0; nt < 4; ++nt) {
        bf16x8v bfr = *(const bf16x8v*)(sm_xst + (nt * 16 + l15) * PS + kk * 32 + quad * 8);
        oacc[0][nt] = __builtin_amdgcn_mfma_f32_16x16x32_bf16(af[0], bfr, oacc[0][nt], 0, 0, 0);
        oacc[1][nt] = __builtin_amdgcn_mfma_f32_16x16x32_bf16(af[1], bfr, oacc[1][nt], 0, 0, 0);
      }
    }
  }

  // ---- epilogue: out = x + K@x, all f32 (residual at full precision) ----
#pragma unroll
  for (int mt = 0; mt < 2; ++mt) {
#pragma unroll
    for (int nt = 0; nt < 4; ++nt) {
#pragma unroll
      for (int reg = 0; reg < 4; ++reg) {
        int row = w * 32 + mt * 16 + quad * 4 + reg;
        int col = nt * 16 + l15;
        size_t idx = (size_t)((size_t)b * T_DIM + t0 + row) * C_DIM + col;
        out[idx] = x[idx] + oacc[mt][nt][reg];
      }
    }
  }
}

extern "C" void kernel_launch(void* const* d_in, const int* in_sizes, int n_in,
                              void* d_out, int out_size, void* d_ws, size_t ws_size,
                              hipStream_t stream) {
  const float* x  = (const float*)d_in[0];
  const float* rs = (const float*)d_in[1];
  float* outp = (float*)d_out;
  int B = in_sizes[0] / (T_DIM * C_DIM);   // 32
  if (B < 1) B = 1;
  dim3 grid(T_DIM / BT, B);
  gauss_attn_f32<<<grid, dim3(256, 1, 1), 0, stream>>>(x, rs, outp);
}

// Round 12
// 208.959 us; speedup vs baseline: 1.2017x; 1.2017x over previous
//
#include <hip/hip_runtime.h>
#include <stdint.h>

// f32 I/O (proven r11). Two-phase: pre_cast builds bf16 X, bf16 X^T, f32 |x|^2
// in d_ws once; gauss_main runs both GEMMs with zero staging conversions and
// ZERO barriers (P tile is wave-private). Fallback to r11 kernel if ws too small.
#define T_DIM 2048
#define C_DIM 64
#define BT 128
#define BS 128
#define PSP 140  // sm_p stride: (4 rows)*(70 dw) % 32 = 24 -> quads hit disjoint banks
#define PS 136   // r11 fallback stride

typedef __bf16 bf16x8v __attribute__((ext_vector_type(8)));
typedef float f32x4 __attribute__((ext_vector_type(4)));

#if defined(__has_builtin)
#if __has_builtin(__builtin_amdgcn_exp2f)
#define EXP2F(x) __builtin_amdgcn_exp2f(x)
#else
#define EXP2F(x) exp2f(x)
#endif
#else
#define EXP2F(x) exp2f(x)
#endif

__device__ __forceinline__ unsigned short f32_to_bf16_rne(float f) {
  union { float f; unsigned int x; } v; v.f = f;
  unsigned int u = v.x;
  u += 0x7fffu + ((u >> 16) & 1u);
  return (unsigned short)(u >> 16);
}
__device__ __forceinline__ uint4 pack8(const unsigned short* v) {
  uint4 u;
  u.x = (unsigned)v[0] | ((unsigned)v[1] << 16);
  u.y = (unsigned)v[2] | ((unsigned)v[3] << 16);
  u.z = (unsigned)v[4] | ((unsigned)v[5] << 16);
  u.w = (unsigned)v[6] | ((unsigned)v[7] << 16);
  return u;
}

// ---------------- pre-pass: f32 -> bf16 X, bf16 X^T, f32 row norms ----------------
__global__ __launch_bounds__(256, 4)
void pre_cast(const float* __restrict__ x, unsigned short* __restrict__ xbf,
              unsigned short* __restrict__ xtbf, float* __restrict__ sq) {
  __shared__ __align__(16) unsigned short tile[64 * 68];
  const int b = blockIdx.y, t0 = blockIdx.x * 64, tid = threadIdx.x;
  const int r = tid >> 2, q = tid & 3;

  const float* src = x + ((size_t)b * T_DIM + t0 + r) * C_DIM + q * 16;
  float part = 0.f;
  unsigned short vals[16];
#pragma unroll
  for (int i = 0; i < 4; ++i) {
    f32x4 v = *(const f32x4*)(src + 4 * i);
#pragma unroll
    for (int j = 0; j < 4; ++j) { part += v[j] * v[j]; vals[4 * i + j] = f32_to_bf16_rne(v[j]); }
  }
  part += __shfl_xor(part, 1);
  part += __shfl_xor(part, 2);
  if (q == 0) sq[(size_t)b * T_DIM + t0 + r] = part;

  uint4 p0 = pack8(vals), p1 = pack8(vals + 8);
  unsigned short* dst = xbf + ((size_t)b * T_DIM + t0 + r) * C_DIM + q * 16;
  *(uint4*)dst = p0;
  *(uint4*)(dst + 8) = p1;
  *(uint4*)(&tile[r * 68 + q * 16]) = p0;
  *(uint4*)(&tile[r * 68 + q * 16 + 8]) = p1;
  __syncthreads();

  const int cc = tid >> 2, tq = tid & 3;  // 4 consecutive lanes share cc -> 128B coalesced stores
  unsigned short tv[16];
#pragma unroll
  for (int j = 0; j < 16; ++j) tv[j] = tile[(tq * 16 + j) * 68 + cc];
  unsigned short* dT = xtbf + ((size_t)b * C_DIM + cc) * T_DIM + t0 + tq * 16;
  *(uint4*)dT = pack8(tv);
  *(uint4*)(dT + 8) = pack8(tv + 8);
}

// ---------------- main: barrier-free fused kernel ----------------
// HW-verified 16x16x32 bf16 MFMA layouts (m89/m91/m97/m120):
//   A: A[m=lane&15][k=(lane>>4)*8+j]; B: lane reads row n of B^T, k-contig
//   C/D: col=lane&15, row=(lane>>4)*4+reg
__global__ __launch_bounds__(256, 2)
void gauss_main(const float* __restrict__ x, const unsigned short* __restrict__ xbf,
                const unsigned short* __restrict__ xtbf, const float* __restrict__ sqn,
                const float* __restrict__ rs, float* __restrict__ out) {
  __shared__ __align__(16) unsigned short sm_p[BT * PSP]; // P bf16 [t][s], wave-private bands

  const int b = blockIdx.y, t0 = blockIdx.x * BT, tid = threadIdx.x;
  const int w = tid >> 6, lane = tid & 63, l15 = lane & 15, quad = lane >> 4;

  float sigma = rs[0];
  if (!(sigma == sigma) || !(sigma >= 0.f) || sigma > 1e3f) sigma = 0.01f;
  const float c1 = sigma * 1.4426950408889634f, c2 = 2.0f * c1;

  const unsigned short* xb  = xbf  + (size_t)b * T_DIM * C_DIM;
  const unsigned short* xtb = xtbf + (size_t)b * C_DIM * T_DIM;
  const float* sqb = sqn + (size_t)b * T_DIM;

  // Q A-frags (b128 from bf16 X)
  bf16x8v qf[2][2];
#pragma unroll
  for (int mt = 0; mt < 2; ++mt)
#pragma unroll
    for (int kk = 0; kk < 2; ++kk)
      qf[mt][kk] = *(const bf16x8v*)(xb + (size_t)(t0 + w * 32 + mt * 16 + l15) * C_DIM + kk * 32 + quad * 8);

  float sTr[2][4];
#pragma unroll
  for (int mt = 0; mt < 2; ++mt)
#pragma unroll
    for (int reg = 0; reg < 4; ++reg)
      sTr[mt][reg] = c1 * sqb[t0 + w * 32 + mt * 16 + quad * 4 + reg];

  f32x4 oacc[2][4];
#pragma unroll
  for (int mt = 0; mt < 2; ++mt)
#pragma unroll
    for (int nt = 0; nt < 4; ++nt)
#pragma unroll
      for (int r = 0; r < 4; ++r) oacc[mt][nt][r] = 0.f;

  for (int it = 0; it < T_DIM / BS; ++it) {
    const int s0 = it * BS;

    float sS[8];
#pragma unroll
    for (int nt = 0; nt < 8; ++nt) sS[nt] = c1 * sqb[s0 + nt * 16 + l15];

    // GEMM1: inner = Q * Xs^T, B-frags b128 from bf16 X
    f32x4 pacc[2][8];
#pragma unroll
    for (int mt = 0; mt < 2; ++mt)
#pragma unroll
      for (int nt = 0; nt < 8; ++nt)
#pragma unroll
        for (int r = 0; r < 4; ++r) pacc[mt][nt][r] = 0.f;

#pragma unroll
    for (int nt = 0; nt < 8; ++nt) {
      const unsigned short* bp = xb + (size_t)(s0 + nt * 16 + l15) * C_DIM + quad * 8;
#pragma unroll
      for (int kk = 0; kk < 2; ++kk) {
        bf16x8v bfr = *(const bf16x8v*)(bp + kk * 32);
        pacc[0][nt] = __builtin_amdgcn_mfma_f32_16x16x32_bf16(qf[0][kk], bfr, pacc[0][nt], 0, 0, 0);
        pacc[1][nt] = __builtin_amdgcn_mfma_f32_16x16x32_bf16(qf[1][kk], bfr, pacc[1][nt], 0, 0, 0);
      }
    }

    // K = exp2(min(c2*inner - c1(|t|^2+|s|^2), 0)) -> bf16 P (wave-private rows)
#pragma unroll
    for (int nt = 0; nt < 8; ++nt) {
#pragma unroll
      for (int mt = 0; mt < 2; ++mt) {
#pragma unroll
        for (int reg = 0; reg < 4; ++reg) {
          float arg = c2 * pacc[mt][nt][reg] - (sTr[mt][reg] + sS[nt]);
          arg = (arg < 0.f) ? arg : 0.f;
          float kv = EXP2F(arg);
          sm_p[(w * 32 + mt * 16 + quad * 4 + reg) * PSP + nt * 16 + l15] = f32_to_bf16_rne(kv);
        }
      }
    }
    // no __syncthreads: each wave reads back only its own 32 rows

    // GEMM2: O += P * Xs; A from sm_p (b128), B from bf16 X^T (b128)
#pragma unroll
    for (int kk = 0; kk < 4; ++kk) {
      bf16x8v af[2];
#pragma unroll
      for (int mt = 0; mt < 2; ++mt)
        af[mt] = *(const bf16x8v*)(sm_p + (w * 32 + mt * 16 + l15) * PSP + kk * 32 + quad * 8);
#pragma unroll
      for (int nt = 0; nt < 4; ++nt) {
        bf16x8v bfr = *(const bf16x8v*)(xtb + (size_t)(nt * 16 + l15) * T_DIM + s0 + kk * 32 + quad * 8);
        oacc[0][nt] = __builtin_amdgcn_mfma_f32_16x16x32_bf16(af[0], bfr, oacc[0][nt], 0, 0, 0);
        oacc[1][nt] = __builtin_amdgcn_mfma_f32_16x16x32_bf16(af[1], bfr, oacc[1][nt], 0, 0, 0);
      }
    }
  }

  // epilogue: out = x + K@x (f32)
#pragma unroll
  for (int mt = 0; mt < 2; ++mt) {
#pragma unroll
    for (int nt = 0; nt < 4; ++nt) {
#pragma unroll
      for (int reg = 0; reg < 4; ++reg) {
        int row = w * 32 + mt * 16 + quad * 4 + reg;
        int col = nt * 16 + l15;
        size_t idx = (size_t)((size_t)b * T_DIM + t0 + row) * C_DIM + col;
        out[idx] = x[idx] + oacc[mt][nt][reg];
      }
    }
  }
}

// ---------------- fallback: proven r11 kernel (ws too small) ----------------
__global__ __launch_bounds__(256, 2)
void gauss_attn_f32(const float* __restrict__ x, const float* __restrict__ rs,
                    float* __restrict__ out) {
  __shared__ __align__(16) unsigned short sm_xst[C_DIM * PS];
  __shared__ __align__(16) unsigned short sm_p[BT * PS];
  __shared__ float sm_sT[BT];
  __shared__ float sm_sS[BS];
  __shared__ float sm_part[2 * BS];

  const int b = blockIdx.y, t0 = blockIdx.x * BT, tid = threadIdx.x;
  const int w = tid >> 6, lane = tid & 63, l15 = lane & 15, quad = lane >> 4;

  float sigma = rs[0];
  if (!(sigma == sigma) || !(sigma >= 0.f) || sigma > 1e3f) sigma = 0.01f;
  const float c1 = sigma * 1.4426950408889634f, c2 = 2.0f * c1;
  const float* xb = x + (size_t)b * T_DIM * C_DIM;

  if (tid < BT) {
    const f32x4* r4 = (const f32x4*)(xb + (size_t)(t0 + tid) * C_DIM);
    float s = 0.f;
#pragma unroll
    for (int i = 0; i < 16; ++i) { f32x4 v = r4[i]; s += v[0]*v[0] + v[1]*v[1] + v[2]*v[2] + v[3]*v[3]; }
    sm_sT[tid] = s;
  }
  bf16x8v qf[2][2];
#pragma unroll
  for (int mt = 0; mt < 2; ++mt) {
    const float* qp = xb + (size_t)(t0 + w * 32 + mt * 16 + l15) * C_DIM + quad * 8;
#pragma unroll
    for (int kk = 0; kk < 2; ++kk) {
      f32x4 a0 = *(const f32x4*)(qp + kk * 32);
      f32x4 a1 = *(const f32x4*)(qp + kk * 32 + 4);
      union { unsigned short u[8]; bf16x8v v; } pk;
#pragma unroll
      for (int j = 0; j < 4; ++j) { pk.u[j] = f32_to_bf16_rne(a0[j]); pk.u[4+j] = f32_to_bf16_rne(a1[j]); }
      qf[mt][kk] = pk.v;
    }
  }
  __syncthreads();
  float sTr[2][4];
#pragma unroll
  for (int mt = 0; mt < 2; ++mt)
#pragma unroll
    for (int reg = 0; reg < 4; ++reg) sTr[mt][reg] = c1 * sm_sT[w * 32 + mt * 16 + quad * 4 + reg];
  f32x4 oacc[2][4];
#pragma unroll
  for (int mt = 0; mt < 2; ++mt)
#pragma unroll
    for (int nt = 0; nt < 4; ++nt)
#pragma unroll
      for (int r = 0; r < 4; ++r) oacc[mt][nt][r] = 0.f;
  const int sidx = tid & 127, h = tid >> 7;
  for (int it = 0; it < T_DIM / BS; ++it) {
    const int s0 = it * BS;
    __syncthreads();
    {
      float part = 0.f;
      const float* sp = xb + (size_t)(s0 + sidx) * C_DIM + h * 32;
#pragma unroll
      for (int r = 0; r < 8; ++r) {
        f32x4 v = *(const f32x4*)(sp + r * 4);
        part += v[0]*v[0] + v[1]*v[1] + v[2]*v[2] + v[3]*v[3];
        const int c0 = h * 32 + r * 4;
        sm_xst[(c0+0)*PS+sidx] = f32_to_bf16_rne(v[0]);
        sm_xst[(c0+1)*PS+sidx] = f32_to_bf16_rne(v[1]);
        sm_xst[(c0+2)*PS+sidx] = f32_to_bf16_rne(v[2]);
        sm_xst[(c0+3)*PS+sidx] = f32_to_bf16_rne(v[3]);
      }
      sm_part[h * BS + sidx] = part;
    }
    __syncthreads();
    if (tid < BS) sm_sS[tid] = sm_part[tid] + sm_part[BS + tid];
    __syncthreads();
    f32x4 pacc[2][8];
#pragma unroll
    for (int mt = 0; mt < 2; ++mt)
#pragma unroll
      for (int nt = 0; nt < 8; ++nt)
#pragma unroll
        for (int r = 0; r < 4; ++r) pacc[mt][nt][r] = 0.f;
#pragma unroll
    for (int nt = 0; nt < 8; ++nt) {
      const float* bp = xb + (size_t)(s0 + nt * 16 + l15) * C_DIM + quad * 8;
#pragma unroll
      for (int kk = 0; kk < 2; ++kk) {
        f32x4 b0 = *(const f32x4*)(bp + kk * 32);
        f32x4 b1 = *(const f32x4*)(bp + kk * 32 + 4);
        union { unsigned short u[8]; bf16x8v v; } pk;
#pragma unroll
        for (int j = 0; j < 4; ++j) { pk.u[j] = f32_to_bf16_rne(b0[j]); pk.u[4+j] = f32_to_bf16_rne(b1[j]); }
        pacc[0][nt] = __builtin_amdgcn_mfma_f32_16x16x32_bf16(qf[0][kk], pk.v, pacc[0][nt], 0, 0, 0);
        pacc[1][nt] = __builtin_amdgcn_mfma_f32_16x16x32_bf16(qf[1][kk], pk.v, pacc[1][nt], 0, 0, 0);
      }
    }
#pragma unroll
    for (int nt = 0; nt < 8; ++nt) {
      const float sSv = c1 * sm_sS[nt * 16 + l15];
#pragma unroll
      for (int mt = 0; mt < 2; ++mt)
#pragma unroll
        for (int reg = 0; reg < 4; ++reg) {
          float arg = c2 * pacc[mt][nt][reg] - (sTr[mt][reg] + sSv);
          arg = (arg < 0.f) ? arg : 0.f;
          sm_p[(w*32+mt*16+quad*4+reg)*PS + nt*16+l15] = f32_to_bf16_rne(EXP2F(arg));
        }
    }
    __syncthreads();
#pragma unroll
    for (int kk = 0; kk < 4; ++kk) {
      bf16x8v af[2];
#pragma unroll
      for (int mt = 0; mt < 2; ++mt)
        af[mt] = *(const bf16x8v*)(sm_p + (w*32+mt*16+l15)*PS + kk*32 + quad*8);
#pragma unroll
      for (int nt = 0; nt < 4; ++nt) {
        bf16x8v bfr = *(const bf16x8v*)(sm_xst + (nt*16+l15)*PS + kk*32 + quad*8);
        oacc[0][nt] = __builtin_amdgcn_mfma_f32_16x16x32_bf16(af[0], bfr, oacc[0][nt], 0, 0, 0);
        oacc[1][nt] = __builtin_amdgcn_mfma_f32_16x16x32_bf16(af[1], bfr, oacc[1][nt], 0, 0, 0);
      }
    }
  }
#pragma unroll
  for (int mt = 0; mt < 2; ++mt)
#pragma unroll
    for (int nt = 0; nt < 4; ++nt)
#pragma unroll
      for (int reg = 0; reg < 4; ++reg) {
        int row = w * 32 + mt * 16 + quad * 4 + reg;
        int col = nt * 16 + l15;
        size_t idx = (size_t)((size_t)b * T_DIM + t0 + row) * C_DIM + col;
        out[idx] = x[idx] + oacc[mt][nt][reg];
      }
}

extern "C" void kernel_launch(void* const* d_in, const int* in_sizes, int n_in,
                              void* d_out, int out_size, void* d_ws, size_t ws_size,
                              hipStream_t stream) {
  const float* x  = (const float*)d_in[0];
  const float* rs = (const float*)d_in[1];
  float* outp = (float*)d_out;
  int B = in_sizes[0] / (T_DIM * C_DIM);
  if (B < 1) B = 1;
  size_t xel = (size_t)B * T_DIM * C_DIM;
  size_t need = xel * 2 * 2 + (size_t)B * T_DIM * 4;
  if (ws_size >= need) {
    unsigned short* xbf  = (unsigned short*)d_ws;
    unsigned short* xtbf = xbf + xel;
    float* sq = (float*)(xtbf + xel);
    pre_cast<<<dim3(T_DIM / 64, B), 256, 0, stream>>>(x, xbf, xtbf, sq);
    gauss_main<<<dim3(T_DIM / BT, B), 256, 0, stream>>>(x, xbf, xtbf, sq, rs, outp);
  } else {
    gauss_attn_f32<<<dim3(T_DIM / BT, B), 256, 0, stream>>>(x, rs, outp);
  }
}